// Round 2
// baseline (8261.326 us; speedup 1.0000x reference)
//
#include <hip/hip_runtime.h>
#include <cstdint>
#include <cstddef>

#define DEVI __device__ __forceinline__

typedef __attribute__((ext_vector_type(8))) short bf16x8;
typedef __attribute__((ext_vector_type(4))) float f32x4;
typedef unsigned short ushort_t;
typedef unsigned int uint_t;

// problem dims (fixed)
constexpr int NB = 64;    // batch
constexpr int NTT = 512;  // seq len
constexpr int NI = 512;   // input feat
constexpr int NH = 1024;  // hidden
constexpr int NA = 512;   // out feat
constexpr int NG = 4096;  // 4*NH
constexpr int CHUNK = 64; // scan chunk (timesteps per launch)

DEVI float bf2f(ushort_t u) { union { uint_t i; float f; } v; v.i = ((uint_t)u) << 16; return v.f; }
DEVI ushort_t f2bf(float f) {
  union { float f; uint_t i; } v; v.f = f;
  uint_t x = v.i;
  return (ushort_t)((x + 0x7fffu + ((x >> 16) & 1u)) >> 16);
}

DEVI void gload_lds16(const void* g, void* l) {
  __builtin_amdgcn_global_load_lds((__attribute__((address_space(1))) void*)g,
                                   (__attribute__((address_space(3))) void*)l, 16, 0, 0);
}

// ---------------- cast fp32 -> bf16 ----------------
__global__ __launch_bounds__(256) void cast_f32_bf16(const float* __restrict__ in,
                                                     ushort_t* __restrict__ out, int n) {
  int i = (blockIdx.x * 256 + threadIdx.x) * 4;
  if (i >= n) return;
  float4 v = *(const float4*)(in + i);
  ushort4 o;
  o.x = f2bf(v.x); o.y = f2bf(v.y); o.z = f2bf(v.z); o.w = f2bf(v.w);
  *(ushort4*)(out + i) = o;
}

// ---------------- generic NT GEMM: C[M,N] = A[M,K] * B[N,K]^T ----------------
// MODE 0: fp32 out, +bias0                              (fc3 -> d_out)
// MODE 1: bf16 out, tanh(acc+bias0)                     (fc1 -> f)
// MODE 2: chunked gx: A rows are (b, t0+tl) of f [B,T,H]; bf16 out,
//         acc+bias0+bias1, scatter to gxc[(tl*NB+b)*NG + n]
template <int MODE>
__global__ __launch_bounds__(256) void gemm_nt(const short* __restrict__ A,
                                               const short* __restrict__ Bm,
                                               const float* __restrict__ bias0,
                                               const float* __restrict__ bias1,
                                               void* __restrict__ Cout,
                                               int M, int N, int K, int t0) {
  __shared__ short As[128 * 32];
  __shared__ short Bs[128 * 32];
  const int tid = threadIdx.x;
  const int wave = tid >> 6, lane = tid & 63;
  const int m0 = blockIdx.y * 128, n0 = blockIdx.x * 128;
  const int wr = wave >> 1, wc = wave & 1;

  f32x4 zero = {0.f, 0.f, 0.f, 0.f};
  f32x4 acc[4][4];
#pragma unroll
  for (int i = 0; i < 4; ++i)
#pragma unroll
    for (int j = 0; j < 4; ++j) acc[i][j] = zero;

  const int lrow = lane >> 2;       // 0..15
  const int lk = (lane & 3) * 8;    // element offset within 32

  for (int kt = 0; kt < K; kt += 32) {
#pragma unroll
    for (int c = 0; c < 2; ++c) {
      int q = wave + 4 * c;              // chunk 0..7, uniform per wave
      int row = m0 + q * 16 + lrow;
      long arow = (MODE == 2) ? ((long)(row >> 6) * NTT + t0 + (row & 63)) : (long)row;
      gload_lds16(A + arow * K + kt + lk, As + q * 512);
      gload_lds16(Bm + (long)(n0 + q * 16 + lrow) * K + kt + lk, Bs + q * 512);
    }
    __syncthreads();  // drains vmcnt for global_load_lds

    bf16x8 av[4], bv[4];
#pragma unroll
    for (int i = 0; i < 4; ++i) {
      int row = wr * 64 + i * 16 + (lane & 15);
      av[i] = *(const bf16x8*)(As + row * 32 + (lane >> 4) * 8);
    }
#pragma unroll
    for (int j = 0; j < 4; ++j) {
      int col = wc * 64 + j * 16 + (lane & 15);
      bv[j] = *(const bf16x8*)(Bs + col * 32 + (lane >> 4) * 8);
    }
#pragma unroll
    for (int i = 0; i < 4; ++i)
#pragma unroll
      for (int j = 0; j < 4; ++j)
        acc[i][j] = __builtin_amdgcn_mfma_f32_16x16x32_bf16(av[i], bv[j], acc[i][j], 0, 0, 0);
    __syncthreads();
  }

  const int fq = lane >> 4, fr = lane & 15;
#pragma unroll
  for (int i = 0; i < 4; ++i) {
#pragma unroll
    for (int j = 0; j < 4; ++j) {
      int gcol = n0 + wc * 64 + j * 16 + fr;
      float bsum = bias0[gcol];
      if (MODE == 2) bsum += bias1[gcol];
#pragma unroll
      for (int r = 0; r < 4; ++r) {
        int gm = m0 + wr * 64 + i * 16 + fq * 4 + r;
        float v = acc[i][j][r] + bsum;
        if (MODE == 0) {
          ((float*)Cout)[(long)gm * N + gcol] = v;
        } else if (MODE == 1) {
          ((ushort_t*)Cout)[(long)gm * N + gcol] = f2bf(tanhf(v));
        } else {
          int b = gm >> 6, tl = gm & 63;  // chunk row = b*64 + tl
          ((ushort_t*)Cout)[(long)(tl * NB + b) * NG + gcol] = f2bf(v);
        }
      }
    }
  }
}

// ---------------- grid barrier (hand-rolled, device scope) ----------------
DEVI void grid_bar(uint_t* bar, uint_t target, int nwg) {
  __syncthreads();
  if (threadIdx.x == 0) {
    __threadfence();  // release
    uint_t old = __hip_atomic_fetch_add(bar, 1u, __ATOMIC_ACQ_REL, __HIP_MEMORY_SCOPE_AGENT);
    if (old == (uint_t)(nwg - 1)) {
      __hip_atomic_store(bar, 0u, __ATOMIC_RELAXED, __HIP_MEMORY_SCOPE_AGENT);
      __hip_atomic_store(bar + 1, target, __ATOMIC_RELEASE, __HIP_MEMORY_SCOPE_AGENT);
    } else {
      while (__hip_atomic_load(bar + 1, __ATOMIC_RELAXED, __HIP_MEMORY_SCOPE_AGENT) < target)
        __builtin_amdgcn_s_sleep(2);
    }
    __threadfence();  // acquire
  }
  __syncthreads();
}

// ---------------- persistent LSTM scan (one chunk of CHUNK timesteps) ----------------
// 64 WGs x 512 threads. WG owns 64 gate rows = 16 hidden units (wg*16+u).
// Local row n = gate*16 + u; global gate row = gate*1024 + wg*16 + u.
// LDS: wlds[64][1024] bf16 XOR-swizzled (byte ^= (n&7)<<4); pre[64][64] fp32.
__global__ __launch_bounds__(512) void lstm_scan(const ushort_t* __restrict__ whh,
                                                 const ushort_t* __restrict__ gxc,  // [CHUNK][NB][NG]
                                                 ushort_t* __restrict__ hbuf,       // [2][NB][NH]
                                                 float* __restrict__ cbuf,          // [NB][NH]
                                                 ushort_t* __restrict__ hs,         // [NB][NTT][NH]
                                                 uint_t* __restrict__ bar,
                                                 int t0, uint_t tbase) {
  extern __shared__ char smem[];
  float* pre = (float*)(smem + 64 * NH * 2);  // 16 KB after 128 KB weights
  const int wg = blockIdx.x, tid = threadIdx.x;
  const int wave = tid >> 6, lane = tid & 63;
  const int fq = lane >> 4, fr = lane & 15;

  // stage weights into swizzled LDS
  for (int idx = tid; idx < 64 * 128; idx += 512) {
    int n = idx >> 7, kc = idx & 127;  // kc: 16B chunk (8 bf16)
    int grow = (n >> 4) * NH + wg * 16 + (n & 15);
    bf16x8 w = *(const bf16x8*)(whh + (long)grow * NH + kc * 8);
    int byteoff = n * 2048 + ((kc * 16) ^ ((n & 7) << 4));
    *(bf16x8*)(smem + byteoff) = w;
  }
  const int cb = tid >> 3, cup = tid & 7;  // this thread owns (b=cb, u=2*cup, 2*cup+1)
  float c0, c1;
  if (t0 == 0) {
    // init h(t=-1) = 0 for owned units (buffer 0), c = 0
    uint_t* p = (uint_t*)(hbuf + cb * NH + wg * 16 + cup * 2);
    __hip_atomic_store(p, 0u, __ATOMIC_RELAXED, __HIP_MEMORY_SCOPE_AGENT);
    c0 = 0.f; c1 = 0.f;
  } else {
    c0 = cbuf[cb * NH + wg * 16 + cup * 2];
    c1 = cbuf[cb * NH + wg * 16 + cup * 2 + 1];
  }
  uint_t bar_t = tbase + 1;
  grid_bar(bar, bar_t++, 64);

  const int bb = (wave & 3) * 16;        // batch base for this wave
  const int nb0 = (wave >> 2) * 32;      // n base (two 16-tiles)
  const int abrow = bb + fr;             // A-frag row (batch)
  f32x4 zero = {0.f, 0.f, 0.f, 0.f};

  for (int tl = 0; tl < CHUNK; ++tl) {
    const int t = t0 + tl;
    const ushort_t* hc = hbuf + (t & 1) * (NB * NH);
    // prefetch gx for this lane's outputs
    float gxv[2][4];
#pragma unroll
    for (int jt = 0; jt < 2; ++jt) {
      int n = nb0 + jt * 16 + fr;
      int grow = (n >> 4) * NH + wg * 16 + (n & 15);
#pragma unroll
      for (int r = 0; r < 4; ++r) {
        int b = bb + fq * 4 + r;
        gxv[jt][r] = bf2f(gxc[(long)(tl * NB + b) * NG + grow]);
      }
    }
    f32x4 acc0 = zero, acc1 = zero;
#pragma unroll
    for (int ks = 0; ks < 32; ++ks) {
      bf16x8 a = *(const bf16x8*)(hc + abrow * NH + ks * 32 + fq * 8);
      int n0 = nb0 + fr, n1 = nb0 + 16 + fr;
      int b0off = n0 * 2048 + ((ks * 64 + fq * 16) ^ ((n0 & 7) << 4));
      int b1off = n1 * 2048 + ((ks * 64 + fq * 16) ^ ((n1 & 7) << 4));
      bf16x8 w0 = *(const bf16x8*)(smem + b0off);
      bf16x8 w1 = *(const bf16x8*)(smem + b1off);
      acc0 = __builtin_amdgcn_mfma_f32_16x16x32_bf16(a, w0, acc0, 0, 0, 0);
      acc1 = __builtin_amdgcn_mfma_f32_16x16x32_bf16(a, w1, acc1, 0, 0, 0);
    }
    // preactivations -> LDS
#pragma unroll
    for (int r = 0; r < 4; ++r) {
      int b = bb + fq * 4 + r;
      pre[b * 64 + nb0 + fr] = acc0[r] + gxv[0][r];
      pre[b * 64 + nb0 + 16 + fr] = acc1[r] + gxv[1][r];
    }
    __syncthreads();
    // gates + state update for (cb, u0, u1)
    float h01[2];
#pragma unroll
    for (int k = 0; k < 2; ++k) {
      int u = cup * 2 + k;
      float xi = pre[cb * 64 + 0 * 16 + u];
      float xf = pre[cb * 64 + 1 * 16 + u];
      float xg = pre[cb * 64 + 2 * 16 + u];
      float xo = pre[cb * 64 + 3 * 16 + u];
      float ig = 1.f / (1.f + __expf(-xi));
      float fg = 1.f / (1.f + __expf(-xf));
      float gg = tanhf(xg);
      float og = 1.f / (1.f + __expf(-xo));
      float& c = k ? c1 : c0;
      c = fg * c + ig * gg;
      h01[k] = og * tanhf(c);
    }
    uint_t hpack = (uint_t)f2bf(h01[0]) | ((uint_t)f2bf(h01[1]) << 16);
    uint_t* hdst = (uint_t*)(hbuf + ((t + 1) & 1) * (NB * NH) + cb * NH + wg * 16 + cup * 2);
    __hip_atomic_store(hdst, hpack, __ATOMIC_RELAXED, __HIP_MEMORY_SCOPE_AGENT);
    // hs write is safe: this chunk's gx GEMM (previous kernel) already consumed f[:,t,:]
    *(uint_t*)(hs + ((long)cb * NTT + t) * NH + wg * 16 + cup * 2) = hpack;
    grid_bar(bar, bar_t++, 64);  // also protects pre[] reuse
  }
  // persist c for next chunk
  cbuf[cb * NH + wg * 16 + cup * 2] = c0;
  cbuf[cb * NH + wg * 16 + cup * 2 + 1] = c1;
}

// ---------------- host ----------------
extern "C" void kernel_launch(void* const* d_in, const int* in_sizes, int n_in,
                              void* d_out, int out_size, void* d_ws, size_t ws_size,
                              hipStream_t stream) {
  const float* x = (const float*)d_in[0];
  const float* w1 = (const float*)d_in[1];
  const float* b1 = (const float*)d_in[2];
  const float* w_ih = (const float*)d_in[3];
  const float* w_hh = (const float*)d_in[4];
  const float* b_ih = (const float*)d_in[5];
  const float* b_hh = (const float*)d_in[6];
  const float* w3 = (const float*)d_in[7];
  const float* b3 = (const float*)d_in[8];

  char* ws = (char*)d_ws;
  size_t off = 0;
  auto alloc = [&](size_t bytes) {
    char* p = ws + off;
    off += (bytes + 255) & ~(size_t)255;
    return p;
  };
  ushort_t* w1b = (ushort_t*)alloc(sizeof(ushort_t) * NH * NI);
  ushort_t* wihb = (ushort_t*)alloc(sizeof(ushort_t) * NG * NH);
  ushort_t* whhb = (ushort_t*)alloc(sizeof(ushort_t) * NG * NH);
  ushort_t* w3b = (ushort_t*)alloc(sizeof(ushort_t) * NA * NH);
  ushort_t* fb = (ushort_t*)alloc(sizeof(ushort_t) * (size_t)NB * NTT * NH);  // f, then hs (in-place)
  float* cbuf = (float*)alloc(sizeof(float) * NB * NH);
  ushort_t* hbuf = (ushort_t*)alloc(sizeof(ushort_t) * 2 * NB * NH);
  uint_t* bar = (uint_t*)alloc(256);
  if (off > ws_size) {
    // sentinel: NaN in d_out -> "ws too small" is distinguishable from no-op
    hipMemsetAsync(d_out, 0xFF, 256, stream);
    return;
  }

  // scratch carved out of d_out (both dead before fc3 writes d_out):
  ushort_t* xb = (ushort_t*)d_out;                       // [B*T*IN] bf16 = 33.5 MB
  ushort_t* gxc = (ushort_t*)d_out + (size_t)NB * NTT * NI;  // [CHUNK][NB][NG] bf16 = 33.5 MB

  auto cast = [&](const float* src, ushort_t* dst, int n) {
    cast_f32_bf16<<<dim3((n / 4 + 255) / 256), dim3(256), 0, stream>>>(src, dst, n);
  };
  cast(x, xb, NB * NTT * NI);
  cast(w1, w1b, NH * NI);
  cast(w_ih, wihb, NG * NH);
  cast(w_hh, whhb, NG * NH);
  cast(w3, w3b, NA * NH);

  // fc1 + tanh -> f (bf16)
  gemm_nt<1><<<dim3(NH / 128, NB * NTT / 128), dim3(256), 0, stream>>>(
      (const short*)xb, (const short*)w1b, b1, nullptr, fb, NB * NTT, NH, NI, 0);

  hipMemsetAsync(bar, 0, 8, stream);
  hipFuncSetAttribute(reinterpret_cast<const void*>(&lstm_scan),
                      hipFuncAttributeMaxDynamicSharedMemorySize, 64 * NH * 2 + 64 * 64 * 4);

  for (int chunk = 0; chunk < NTT / CHUNK; ++chunk) {
    int t0 = chunk * CHUNK;
    // gx chunk: rows (b, t0..t0+CHUNK-1) of f -> gxc [tl][b][4096]
    gemm_nt<2><<<dim3(NG / 128, NB * CHUNK / 128), dim3(256), 0, stream>>>(
        (const short*)fb, (const short*)wihb, b_ih, b_hh, gxc, NB * CHUNK, NG, NH, t0);
    lstm_scan<<<dim3(64), dim3(512), 64 * NH * 2 + 64 * 64 * 4, stream>>>(
        whhb, gxc, hbuf, cbuf, fb, bar, t0, (uint_t)(chunk * (CHUNK + 1)));
  }

  // fc3 head -> d_out (fp32)
  gemm_nt<0><<<dim3(NA / 128, NB * NTT / 128), dim3(256), 0, stream>>>(
      (const short*)fb, (const short*)w3b, b3, nullptr, d_out, NB * NTT, NA, NH, 0);
}

// Round 3
// 6990.974 us; speedup vs baseline: 1.1817x; 1.1817x over previous
//
#include <hip/hip_runtime.h>
#include <cstdint>
#include <cstddef>

#define DEVI __device__ __forceinline__

typedef __attribute__((ext_vector_type(8))) short bf16x8;
typedef __attribute__((ext_vector_type(4))) float f32x4;
typedef unsigned short ushort_t;
typedef unsigned int uint_t;

// problem dims (fixed)
constexpr int NB = 64;    // batch
constexpr int NTT = 512;  // seq len
constexpr int NI = 512;   // input feat
constexpr int NH = 1024;  // hidden
constexpr int NA = 512;   // out feat
constexpr int NG = 4096;  // 4*NH
constexpr int CHUNK = 64; // scan chunk (timesteps per launch)

DEVI float bf2f(ushort_t u) { union { uint_t i; float f; } v; v.i = ((uint_t)u) << 16; return v.f; }
DEVI ushort_t f2bf(float f) {
  union { float f; uint_t i; } v; v.f = f;
  uint_t x = v.i;
  return (ushort_t)((x + 0x7fffu + ((x >> 16) & 1u)) >> 16);
}

DEVI void gload_lds16(const void* g, void* l) {
  __builtin_amdgcn_global_load_lds((__attribute__((address_space(1))) void*)g,
                                   (__attribute__((address_space(3))) void*)l, 16, 0, 0);
}

// ---------------- cast fp32 -> bf16 ----------------
__global__ __launch_bounds__(256) void cast_f32_bf16(const float* __restrict__ in,
                                                     ushort_t* __restrict__ out, int n) {
  int i = (blockIdx.x * 256 + threadIdx.x) * 4;
  if (i >= n) return;
  float4 v = *(const float4*)(in + i);
  ushort4 o;
  o.x = f2bf(v.x); o.y = f2bf(v.y); o.z = f2bf(v.z); o.w = f2bf(v.w);
  *(ushort4*)(out + i) = o;
}

// ---------------- generic NT GEMM: C[M,N] = A[M,K] * B[N,K]^T ----------------
// MODE 0: fp32 out, +bias0                              (fc3 -> d_out)
// MODE 1: bf16 out, tanh(acc+bias0)                     (fc1 -> f)
// MODE 2: chunked gx: A rows are (b, t0+tl) of f [B,T,H]; bf16 out,
//         acc+bias0+bias1, scatter to gxc[tl][wg][b][g*16+u]
template <int MODE>
__global__ __launch_bounds__(256) void gemm_nt(const short* __restrict__ A,
                                               const short* __restrict__ Bm,
                                               const float* __restrict__ bias0,
                                               const float* __restrict__ bias1,
                                               void* __restrict__ Cout,
                                               int M, int N, int K, int t0) {
  __shared__ short As[128 * 32];
  __shared__ short Bs[128 * 32];
  const int tid = threadIdx.x;
  const int wave = tid >> 6, lane = tid & 63;
  const int m0 = blockIdx.y * 128, n0 = blockIdx.x * 128;
  const int wr = wave >> 1, wc = wave & 1;

  f32x4 zero = {0.f, 0.f, 0.f, 0.f};
  f32x4 acc[4][4];
#pragma unroll
  for (int i = 0; i < 4; ++i)
#pragma unroll
    for (int j = 0; j < 4; ++j) acc[i][j] = zero;

  const int lrow = lane >> 2;       // 0..15
  const int lk = (lane & 3) * 8;    // element offset within 32

  for (int kt = 0; kt < K; kt += 32) {
#pragma unroll
    for (int c = 0; c < 2; ++c) {
      int q = wave + 4 * c;              // chunk 0..7, uniform per wave
      int row = m0 + q * 16 + lrow;
      long arow = (MODE == 2) ? ((long)(row >> 6) * NTT + t0 + (row & 63)) : (long)row;
      gload_lds16(A + arow * K + kt + lk, As + q * 512);
      gload_lds16(Bm + (long)(n0 + q * 16 + lrow) * K + kt + lk, Bs + q * 512);
    }
    __syncthreads();  // drains vmcnt for global_load_lds

    bf16x8 av[4], bv[4];
#pragma unroll
    for (int i = 0; i < 4; ++i) {
      int row = wr * 64 + i * 16 + (lane & 15);
      av[i] = *(const bf16x8*)(As + row * 32 + (lane >> 4) * 8);
    }
#pragma unroll
    for (int j = 0; j < 4; ++j) {
      int col = wc * 64 + j * 16 + (lane & 15);
      bv[j] = *(const bf16x8*)(Bs + col * 32 + (lane >> 4) * 8);
    }
#pragma unroll
    for (int i = 0; i < 4; ++i)
#pragma unroll
      for (int j = 0; j < 4; ++j)
        acc[i][j] = __builtin_amdgcn_mfma_f32_16x16x32_bf16(av[i], bv[j], acc[i][j], 0, 0, 0);
    __syncthreads();
  }

  const int fq = lane >> 4, fr = lane & 15;
#pragma unroll
  for (int i = 0; i < 4; ++i) {
#pragma unroll
    for (int j = 0; j < 4; ++j) {
      int gcol = n0 + wc * 64 + j * 16 + fr;
      float bsum = bias0[gcol];
      if (MODE == 2) bsum += bias1[gcol];
#pragma unroll
      for (int r = 0; r < 4; ++r) {
        int gm = m0 + wr * 64 + i * 16 + fq * 4 + r;
        float v = acc[i][j][r] + bsum;
        if (MODE == 0) {
          ((float*)Cout)[(long)gm * N + gcol] = v;
        } else if (MODE == 1) {
          ((ushort_t*)Cout)[(long)gm * N + gcol] = f2bf(tanhf(v));
        } else {
          int b = gm >> 6, tl = gm & 63;  // chunk row = b*64 + tl
          int wgp = (gcol >> 4) & 63, g = gcol >> 10, u = gcol & 15;
          ((ushort_t*)Cout)[((((long)tl * 64 + wgp) * 64 + b) << 6) + g * 16 + u] = f2bf(v);
        }
      }
    }
  }
}

// ---------------- persistent LSTM scan (one chunk of CHUNK timesteps) ----------------
// 64 WGs x 512 threads. WG owns 64 gate rows = 16 hidden units (wg*16+u).
// Local row n = gate*16 + u; global gate row = gate*1024 + wg*16 + u.
// LDS: wlds[64][1024] bf16 XOR-swizzled (byte ^= (n&7)<<4); pre[64][65] fp32.
// h passes through rotating hseq slots (sc1 stores, plain cacheable loads).
// Grid sync: all-to-all per-WG flags (128B apart), wave0 polls all 64.
__global__ __launch_bounds__(512) void lstm_scan(const ushort_t* __restrict__ whh,
                                                 const ushort_t* __restrict__ gxc,  // [CHUNK][64][NB][64]
                                                 ushort_t* __restrict__ hseq,       // [CHUNK+1][NB][NH]
                                                 float* __restrict__ cbuf,          // [NB][NH]
                                                 ushort_t* __restrict__ hs,         // [NB][NTT][NH]
                                                 uint_t* __restrict__ flags,
                                                 int t0, uint_t tbase) {
  extern __shared__ char smem[];
  float* pre = (float*)(smem + 64 * NH * 2);  // [64][65] fp32
  const int wg = blockIdx.x, tid = threadIdx.x;
  const int wave = tid >> 6, lane = tid & 63;
  const int fq = lane >> 4, fr = lane & 15;

  // stage weights into swizzled LDS
  for (int idx = tid; idx < 64 * 128; idx += 512) {
    int n = idx >> 7, kc = idx & 127;  // kc: 16B chunk (8 bf16)
    int grow = (n >> 4) * NH + wg * 16 + (n & 15);
    bf16x8 w = *(const bf16x8*)(whh + (long)grow * NH + kc * 8);
    int byteoff = n * 2048 + ((kc * 16) ^ ((n & 7) << 4));
    *(bf16x8*)(smem + byteoff) = w;
  }
  const int cb = tid >> 3, cup = tid & 7;  // thread owns (b=cb, u=2*cup, 2*cup+1)
  float c0, c1;
  if (t0 == 0) {
    uint_t* p = (uint_t*)(hseq + cb * NH + wg * 16 + cup * 2);
    __hip_atomic_store(p, 0u, __ATOMIC_RELAXED, __HIP_MEMORY_SCOPE_AGENT);
    c0 = 0.f; c1 = 0.f;
  } else {
    c0 = cbuf[cb * NH + wg * 16 + cup * 2];
    c1 = cbuf[cb * NH + wg * 16 + cup * 2 + 1];
  }

  const int bb = (wave & 3) * 16;        // batch base for this wave
  const int nb0 = (wave >> 2) * 32;      // n base (two 16-tiles)
  const int abrow = bb + fr;             // A-frag row (batch)
  f32x4 zero = {0.f, 0.f, 0.f, 0.f};

  ushort_t gxr[8];
  auto prefetch = [&](int tl) {
#pragma unroll
    for (int jt = 0; jt < 2; ++jt) {
      int n = nb0 + jt * 16 + fr;
#pragma unroll
      for (int r = 0; r < 4; ++r) {
        int b = bb + fq * 4 + r;
        gxr[jt * 4 + r] = gxc[((((long)tl * 64 + wg) * 64 + b) << 6) + n];
      }
    }
  };
  auto arrive = [&](uint_t t) {
    if (tid == 0)
      __hip_atomic_store(flags + wg * 32, t, __ATOMIC_RELEASE, __HIP_MEMORY_SCOPE_AGENT);
  };
  auto poll = [&](uint_t t) {
    if (tid < 64) {
      uint_t* fp = flags + tid * 32;
      for (;;) {
        uint_t v = __hip_atomic_load(fp, __ATOMIC_RELAXED, __HIP_MEMORY_SCOPE_AGENT);
        if (__all(v >= t)) break;
        __builtin_amdgcn_s_sleep(1);
      }
    }
  };

  // initial barrier: weights staged, h slot0 + c ready
  __syncthreads();
  arrive(tbase + 1);
  prefetch(0);
  poll(tbase + 1);
  __syncthreads();

  for (int tl = 0; tl < CHUNK; ++tl) {
    const ushort_t* hc = hseq + (size_t)tl * (NB * NH);
    f32x4 acc0 = zero, acc1 = zero;
#pragma unroll
    for (int ks = 0; ks < 32; ++ks) {
      bf16x8 a = *(const bf16x8*)(hc + abrow * NH + ks * 32 + fq * 8);
      int n0 = nb0 + fr, n1 = nb0 + 16 + fr;
      int b0off = n0 * 2048 + ((ks * 64 + fq * 16) ^ ((n0 & 7) << 4));
      int b1off = n1 * 2048 + ((ks * 64 + fq * 16) ^ ((n1 & 7) << 4));
      bf16x8 w0 = *(const bf16x8*)(smem + b0off);
      bf16x8 w1 = *(const bf16x8*)(smem + b1off);
      acc0 = __builtin_amdgcn_mfma_f32_16x16x32_bf16(a, w0, acc0, 0, 0, 0);
      acc1 = __builtin_amdgcn_mfma_f32_16x16x32_bf16(a, w1, acc1, 0, 0, 0);
    }
    // preactivations (+gx) -> LDS
#pragma unroll
    for (int r = 0; r < 4; ++r) {
      int b = bb + fq * 4 + r;
      pre[b * 65 + nb0 + fr] = acc0[r] + bf2f(gxr[r]);
      pre[b * 65 + nb0 + 16 + fr] = acc1[r] + bf2f(gxr[4 + r]);
    }
    __syncthreads();
    // gates + state update for (cb, u0, u1)
    float h01[2];
#pragma unroll
    for (int k = 0; k < 2; ++k) {
      int u = cup * 2 + k;
      float xi = pre[cb * 65 + 0 * 16 + u];
      float xf = pre[cb * 65 + 1 * 16 + u];
      float xg = pre[cb * 65 + 2 * 16 + u];
      float xo = pre[cb * 65 + 3 * 16 + u];
      float ig = 1.f / (1.f + __expf(-xi));
      float fg = 1.f / (1.f + __expf(-xf));
      float gg = tanhf(xg);
      float og = 1.f / (1.f + __expf(-xo));
      float& c = k ? c1 : c0;
      c = fg * c + ig * gg;
      h01[k] = og * tanhf(c);
    }
    uint_t hpack = (uint_t)f2bf(h01[0]) | ((uint_t)f2bf(h01[1]) << 16);
    uint_t* hdst = (uint_t*)(hseq + (size_t)(tl + 1) * (NB * NH) + cb * NH + wg * 16 + cup * 2);
    __hip_atomic_store(hdst, hpack, __ATOMIC_RELAXED, __HIP_MEMORY_SCOPE_AGENT);
    if (tl == CHUNK - 1) {  // hand h(final) to next chunk's slot 0 (slot 0 reads long done)
      uint_t* h0 = (uint_t*)(hseq + cb * NH + wg * 16 + cup * 2);
      __hip_atomic_store(h0, hpack, __ATOMIC_RELAXED, __HIP_MEMORY_SCOPE_AGENT);
    }
    *(uint_t*)(hs + ((size_t)cb * NTT + t0 + tl) * NH + wg * 16 + cup * 2) = hpack;

    // ---- grid barrier (prefetch overlapped with poll) ----
    __syncthreads();  // per-thread vmcnt drain: h stores done before flag
    uint_t t = tbase + 2 + tl;
    arrive(t);
    if (tl + 1 < CHUNK) prefetch(tl + 1);
    poll(t);
    __syncthreads();
    asm volatile("" ::: "memory");
  }
  // persist c for next chunk
  cbuf[cb * NH + wg * 16 + cup * 2] = c0;
  cbuf[cb * NH + wg * 16 + cup * 2 + 1] = c1;
}

// ---------------- host ----------------
extern "C" void kernel_launch(void* const* d_in, const int* in_sizes, int n_in,
                              void* d_out, int out_size, void* d_ws, size_t ws_size,
                              hipStream_t stream) {
  const float* x = (const float*)d_in[0];
  const float* w1 = (const float*)d_in[1];
  const float* b1 = (const float*)d_in[2];
  const float* w_ih = (const float*)d_in[3];
  const float* w_hh = (const float*)d_in[4];
  const float* b_ih = (const float*)d_in[5];
  const float* b_hh = (const float*)d_in[6];
  const float* w3 = (const float*)d_in[7];
  const float* b3 = (const float*)d_in[8];

  char* ws = (char*)d_ws;
  size_t off = 0;
  auto alloc = [&](size_t bytes) {
    char* p = ws + off;
    off += (bytes + 255) & ~(size_t)255;
    return p;
  };
  ushort_t* w1b = (ushort_t*)alloc(sizeof(ushort_t) * NH * NI);
  ushort_t* wihb = (ushort_t*)alloc(sizeof(ushort_t) * NG * NH);
  ushort_t* whhb = (ushort_t*)alloc(sizeof(ushort_t) * NG * NH);
  ushort_t* w3b = (ushort_t*)alloc(sizeof(ushort_t) * NA * NH);
  ushort_t* fb = (ushort_t*)alloc(sizeof(ushort_t) * (size_t)NB * NTT * NH);  // f, then hs (in-place)
  float* cbuf = (float*)alloc(sizeof(float) * NB * NH);
  uint_t* flags = (uint_t*)alloc(sizeof(uint_t) * 64 * 32);
  if (off > ws_size) {
    hipMemsetAsync(d_out, 0xFF, 256, stream);  // NaN sentinel: ws too small
    return;
  }

  // scratch carved out of d_out (dead before fc3 writes d_out):
  // [0, 33.5MB): xb (bf16 x) for fc1, then reused as hseq for the scan
  // [33.5MB, 67MB): gxc chunk buffer
  ushort_t* xb = (ushort_t*)d_out;
  ushort_t* hseq = (ushort_t*)d_out;                         // [CHUNK+1][NB][NH] = 8.5MB
  ushort_t* gxc = (ushort_t*)d_out + (size_t)NB * NTT * NI;  // [CHUNK][64][NB][64] = 33.5MB

  auto cast = [&](const float* src, ushort_t* dst, int n) {
    cast_f32_bf16<<<dim3((n / 4 + 255) / 256), dim3(256), 0, stream>>>(src, dst, n);
  };
  cast(x, xb, NB * NTT * NI);
  cast(w1, w1b, NH * NI);
  cast(w_ih, wihb, NG * NH);
  cast(w_hh, whhb, NG * NH);
  cast(w3, w3b, NA * NH);

  // fc1 + tanh -> f (bf16)
  gemm_nt<1><<<dim3(NH / 128, NB * NTT / 128), dim3(256), 0, stream>>>(
      (const short*)xb, (const short*)w1b, b1, nullptr, fb, NB * NTT, NH, NI, 0);

  hipMemsetAsync(flags, 0, sizeof(uint_t) * 64 * 32, stream);
  int ldsz = 64 * NH * 2 + 64 * 65 * 4;
  hipFuncSetAttribute(reinterpret_cast<const void*>(&lstm_scan),
                      hipFuncAttributeMaxDynamicSharedMemorySize, ldsz);

  for (int chunk = 0; chunk < NTT / CHUNK; ++chunk) {
    int t0 = chunk * CHUNK;
    gemm_nt<2><<<dim3(NG / 128, NB * CHUNK / 128), dim3(256), 0, stream>>>(
        (const short*)fb, (const short*)wihb, b_ih, b_hh, gxc, NB * CHUNK, NG, NH, t0);
    lstm_scan<<<dim3(64), dim3(512), ldsz, stream>>>(
        whhb, gxc, hseq, cbuf, fb, flags, t0, (uint_t)(chunk * (CHUNK + 1)));
  }

  // fc3 head -> d_out (fp32)
  gemm_nt<0><<<dim3(NA / 128, NB * NTT / 128), dim3(256), 0, stream>>>(
      (const short*)fb, (const short*)w3b, b3, nullptr, d_out, NB * NTT, NA, NH, 0);
}

// Round 4
// 6362.038 us; speedup vs baseline: 1.2985x; 1.0989x over previous
//
#include <hip/hip_runtime.h>
#include <cstdint>
#include <cstddef>

#define DEVI __device__ __forceinline__

typedef __attribute__((ext_vector_type(8))) short bf16x8;
typedef __attribute__((ext_vector_type(4))) float f32x4;
typedef unsigned short ushort_t;
typedef unsigned int uint_t;

// problem dims (fixed)
constexpr int NB = 64;    // batch
constexpr int NTT = 512;  // seq len
constexpr int NI = 512;   // input feat
constexpr int NH = 1024;  // hidden
constexpr int NA = 512;   // out feat
constexpr int NG = 4096;  // 4*NH
constexpr int CHUNK = 64; // scan chunk (timesteps per launch)

DEVI float bf2f(ushort_t u) { union { uint_t i; float f; } v; v.i = ((uint_t)u) << 16; return v.f; }
DEVI ushort_t f2bf(float f) {
  union { float f; uint_t i; } v; v.f = f;
  uint_t x = v.i;
  return (ushort_t)((x + 0x7fffu + ((x >> 16) & 1u)) >> 16);
}

DEVI void gload_lds16(const void* g, void* l) {
  __builtin_amdgcn_global_load_lds((__attribute__((address_space(1))) void*)g,
                                   (__attribute__((address_space(3))) void*)l, 16, 0, 0);
}

// ---------------- cast fp32 -> bf16 ----------------
__global__ __launch_bounds__(256) void cast_f32_bf16(const float* __restrict__ in,
                                                     ushort_t* __restrict__ out, int n) {
  int i = (blockIdx.x * 256 + threadIdx.x) * 4;
  if (i >= n) return;
  float4 v = *(const float4*)(in + i);
  ushort4 o;
  o.x = f2bf(v.x); o.y = f2bf(v.y); o.z = f2bf(v.z); o.w = f2bf(v.w);
  *(ushort4*)(out + i) = o;
}

// ---------------- generic NT GEMM: C[M,N] = A[M,K] * B[N,K]^T ----------------
// MODE 0: fp32 out, +bias0                              (fc3 -> d_out)
// MODE 1: bf16 out, tanh(acc+bias0)                     (fc1 -> f)
// MODE 2: chunked gx: A rows are (b, t0+tl) of f [B,T,H]; bf16 out,
//         acc+bias0+bias1, scatter to gxc[tl][wg][b][g*16+u]
template <int MODE>
__global__ __launch_bounds__(256) void gemm_nt(const short* __restrict__ A,
                                               const short* __restrict__ Bm,
                                               const float* __restrict__ bias0,
                                               const float* __restrict__ bias1,
                                               void* __restrict__ Cout,
                                               int M, int N, int K, int t0) {
  __shared__ short As[128 * 32];
  __shared__ short Bs[128 * 32];
  const int tid = threadIdx.x;
  const int wave = tid >> 6, lane = tid & 63;
  const int m0 = blockIdx.y * 128, n0 = blockIdx.x * 128;
  const int wr = wave >> 1, wc = wave & 1;

  f32x4 zero = {0.f, 0.f, 0.f, 0.f};
  f32x4 acc[4][4];
#pragma unroll
  for (int i = 0; i < 4; ++i)
#pragma unroll
    for (int j = 0; j < 4; ++j) acc[i][j] = zero;

  const int lrow = lane >> 2;       // 0..15
  const int lk = (lane & 3) * 8;    // element offset within 32

  for (int kt = 0; kt < K; kt += 32) {
#pragma unroll
    for (int c = 0; c < 2; ++c) {
      int q = wave + 4 * c;              // chunk 0..7, uniform per wave
      int row = m0 + q * 16 + lrow;
      long arow = (MODE == 2) ? ((long)(row >> 6) * NTT + t0 + (row & 63)) : (long)row;
      gload_lds16(A + arow * K + kt + lk, As + q * 512);
      gload_lds16(Bm + (long)(n0 + q * 16 + lrow) * K + kt + lk, Bs + q * 512);
    }
    __syncthreads();  // drains vmcnt for global_load_lds

    bf16x8 av[4], bv[4];
#pragma unroll
    for (int i = 0; i < 4; ++i) {
      int row = wr * 64 + i * 16 + (lane & 15);
      av[i] = *(const bf16x8*)(As + row * 32 + (lane >> 4) * 8);
    }
#pragma unroll
    for (int j = 0; j < 4; ++j) {
      int col = wc * 64 + j * 16 + (lane & 15);
      bv[j] = *(const bf16x8*)(Bs + col * 32 + (lane >> 4) * 8);
    }
#pragma unroll
    for (int i = 0; i < 4; ++i)
#pragma unroll
      for (int j = 0; j < 4; ++j)
        acc[i][j] = __builtin_amdgcn_mfma_f32_16x16x32_bf16(av[i], bv[j], acc[i][j], 0, 0, 0);
    __syncthreads();
  }

  const int fq = lane >> 4, fr = lane & 15;
#pragma unroll
  for (int i = 0; i < 4; ++i) {
#pragma unroll
    for (int j = 0; j < 4; ++j) {
      int gcol = n0 + wc * 64 + j * 16 + fr;
      float bsum = bias0[gcol];
      if (MODE == 2) bsum += bias1[gcol];
#pragma unroll
      for (int r = 0; r < 4; ++r) {
        int gm = m0 + wr * 64 + i * 16 + fq * 4 + r;
        float v = acc[i][j][r] + bsum;
        if (MODE == 0) {
          ((float*)Cout)[(long)gm * N + gcol] = v;
        } else if (MODE == 1) {
          ((ushort_t*)Cout)[(long)gm * N + gcol] = f2bf(tanhf(v));
        } else {
          int b = gm >> 6, tl = gm & 63;  // chunk row = b*64 + tl
          int wgp = (gcol >> 4) & 63, g = gcol >> 10, u = gcol & 15;
          ((ushort_t*)Cout)[((((long)tl * 64 + wgp) * 64 + b) << 6) + g * 16 + u] = f2bf(v);
        }
      }
    }
  }
}

// ---------------- persistent LSTM scan (one chunk of CHUNK timesteps) ----------------
// 64 WGs x 512 threads. WG owns 64 gate rows = 16 hidden units (wg*16+u).
// Local row n = gate*16 + u; global gate row = gate*1024 + wg*16 + u.
// LDS: wlds[64][1024] bf16 XOR-swizzled (byte ^= (n&7)<<4); pre[64][65] fp32.
// h passes through rotating hseq slots (relaxed agent stores -> LLC; plain loads).
// Grid sync: per-WG flag cachelines; wave0 polls all 64. NO release/fence:
// payload stores are agent-atomics, so s_waitcnt vmcnt(0) before the flag store
// is a sufficient release (avoids buffer_wbl2 = full L2 writeback per step).
__global__ __launch_bounds__(512) void lstm_scan(const ushort_t* __restrict__ whh,
                                                 const ushort_t* __restrict__ gxc,  // [CHUNK][64][NB][64]
                                                 ushort_t* __restrict__ hseq,       // [CHUNK+1][NB][NH]
                                                 float* __restrict__ cbuf,          // [NB][NH]
                                                 ushort_t* __restrict__ hs,         // [NB][NTT][NH]
                                                 uint_t* __restrict__ flags,
                                                 int t0, uint_t tbase) {
  extern __shared__ char smem[];
  float* pre = (float*)(smem + 64 * NH * 2);  // [64][65] fp32
  const int wg = blockIdx.x, tid = threadIdx.x;
  const int wave = tid >> 6, lane = tid & 63;
  const int fq = lane >> 4, fr = lane & 15;

  // stage weights into swizzled LDS
  for (int idx = tid; idx < 64 * 128; idx += 512) {
    int n = idx >> 7, kc = idx & 127;  // kc: 16B chunk (8 bf16)
    int grow = (n >> 4) * NH + wg * 16 + (n & 15);
    bf16x8 w = *(const bf16x8*)(whh + (long)grow * NH + kc * 8);
    int byteoff = n * 2048 + ((kc * 16) ^ ((n & 7) << 4));
    *(bf16x8*)(smem + byteoff) = w;
  }
  const int cb = tid >> 3, cup = tid & 7;  // thread owns (b=cb, u=2*cup, 2*cup+1)
  float c0, c1;
  if (t0 == 0) {
    uint_t* p = (uint_t*)(hseq + cb * NH + wg * 16 + cup * 2);
    __hip_atomic_store(p, 0u, __ATOMIC_RELAXED, __HIP_MEMORY_SCOPE_AGENT);
    c0 = 0.f; c1 = 0.f;
  } else {
    c0 = cbuf[cb * NH + wg * 16 + cup * 2];
    c1 = cbuf[cb * NH + wg * 16 + cup * 2 + 1];
  }

  const int bb = (wave & 3) * 16;        // batch base for this wave
  const int nb0 = (wave >> 2) * 32;      // n base (two 16-tiles)
  const int abrow = bb + fr;             // A-frag row (batch)
  f32x4 zero = {0.f, 0.f, 0.f, 0.f};

  ushort_t gxr[8];
  auto prefetch = [&](int tl) {
#pragma unroll
    for (int jt = 0; jt < 2; ++jt) {
      int n = nb0 + jt * 16 + fr;
#pragma unroll
      for (int r = 0; r < 4; ++r) {
        int b = bb + fq * 4 + r;
        gxr[jt * 4 + r] = gxc[((((long)tl * 64 + wg) * 64 + b) << 6) + n];
      }
    }
  };
  auto poll = [&](uint_t t) {
    if (tid < 64) {
      uint_t* fp = flags + tid * 32;
      for (;;) {
        uint_t v = __hip_atomic_load(fp, __ATOMIC_RELAXED, __HIP_MEMORY_SCOPE_AGENT);
        if (__all(v >= t)) break;
        __builtin_amdgcn_s_sleep(1);
      }
    }
  };

  // initial barrier: weights staged, h slot0 + c ready
  asm volatile("s_waitcnt vmcnt(0)" ::: "memory");
  __syncthreads();
  if (tid == 0)
    __hip_atomic_store(flags + wg * 32, tbase + 1, __ATOMIC_RELAXED, __HIP_MEMORY_SCOPE_AGENT);
  prefetch(0);
  poll(tbase + 1);
  __syncthreads();

  for (int tl = 0; tl < CHUNK; ++tl) {
    const ushort_t* hc = hseq + (size_t)tl * (NB * NH);
    f32x4 acc0 = zero, acc1 = zero;
#pragma unroll
    for (int ks = 0; ks < 32; ++ks) {
      bf16x8 a = *(const bf16x8*)(hc + abrow * NH + ks * 32 + fq * 8);
      int n0 = nb0 + fr, n1 = nb0 + 16 + fr;
      int b0off = n0 * 2048 + ((ks * 64 + fq * 16) ^ ((n0 & 7) << 4));
      int b1off = n1 * 2048 + ((ks * 64 + fq * 16) ^ ((n1 & 7) << 4));
      bf16x8 w0 = *(const bf16x8*)(smem + b0off);
      bf16x8 w1 = *(const bf16x8*)(smem + b1off);
      acc0 = __builtin_amdgcn_mfma_f32_16x16x32_bf16(a, w0, acc0, 0, 0, 0);
      acc1 = __builtin_amdgcn_mfma_f32_16x16x32_bf16(a, w1, acc1, 0, 0, 0);
    }
    // preactivations (+gx) -> LDS
#pragma unroll
    for (int r = 0; r < 4; ++r) {
      int b = bb + fq * 4 + r;
      pre[b * 65 + nb0 + fr] = acc0[r] + bf2f(gxr[r]);
      pre[b * 65 + nb0 + 16 + fr] = acc1[r] + bf2f(gxr[4 + r]);
    }
    __syncthreads();
    // gates + state update for (cb, u0, u1)
    float h01[2];
#pragma unroll
    for (int k = 0; k < 2; ++k) {
      int u = cup * 2 + k;
      float xi = pre[cb * 65 + 0 * 16 + u];
      float xf = pre[cb * 65 + 1 * 16 + u];
      float xg = pre[cb * 65 + 2 * 16 + u];
      float xo = pre[cb * 65 + 3 * 16 + u];
      float ig = 1.f / (1.f + __expf(-xi));
      float fg = 1.f / (1.f + __expf(-xf));
      float gg = tanhf(xg);
      float og = 1.f / (1.f + __expf(-xo));
      float& c = k ? c1 : c0;
      c = fg * c + ig * gg;
      h01[k] = og * tanhf(c);
    }
    uint_t hpack = (uint_t)f2bf(h01[0]) | ((uint_t)f2bf(h01[1]) << 16);
    uint_t* hdst = (uint_t*)(hseq + (size_t)(tl + 1) * (NB * NH) + cb * NH + wg * 16 + cup * 2);
    __hip_atomic_store(hdst, hpack, __ATOMIC_RELAXED, __HIP_MEMORY_SCOPE_AGENT);
    if (tl == CHUNK - 1) {  // hand h(final) to next chunk's slot 0
      uint_t* h0 = (uint_t*)(hseq + cb * NH + wg * 16 + cup * 2);
      __hip_atomic_store(h0, hpack, __ATOMIC_RELAXED, __HIP_MEMORY_SCOPE_AGENT);
    }

    // ---- grid barrier: vmcnt-drain release, no wbl2 ----
    asm volatile("s_waitcnt vmcnt(0)" ::: "memory");  // h atomic stores acked at LLC
    __syncthreads();                                  // all threads of WG drained
    uint_t t = tbase + 2 + tl;
    if (tid == 0)
      __hip_atomic_store(flags + wg * 32, t, __ATOMIC_RELAXED, __HIP_MEMORY_SCOPE_AGENT);
    // off-critical-path work overlapped with the wait:
    *(uint_t*)(hs + ((size_t)cb * NTT + t0 + tl) * NH + wg * 16 + cup * 2) = hpack;
    if (tl + 1 < CHUNK) prefetch(tl + 1);
    poll(t);
    __syncthreads();
    asm volatile("" ::: "memory");
  }
  // persist c for next chunk
  cbuf[cb * NH + wg * 16 + cup * 2] = c0;
  cbuf[cb * NH + wg * 16 + cup * 2 + 1] = c1;
}

// ---------------- host ----------------
extern "C" void kernel_launch(void* const* d_in, const int* in_sizes, int n_in,
                              void* d_out, int out_size, void* d_ws, size_t ws_size,
                              hipStream_t stream) {
  const float* x = (const float*)d_in[0];
  const float* w1 = (const float*)d_in[1];
  const float* b1 = (const float*)d_in[2];
  const float* w_ih = (const float*)d_in[3];
  const float* w_hh = (const float*)d_in[4];
  const float* b_ih = (const float*)d_in[5];
  const float* b_hh = (const float*)d_in[6];
  const float* w3 = (const float*)d_in[7];
  const float* b3 = (const float*)d_in[8];

  char* ws = (char*)d_ws;
  size_t off = 0;
  auto alloc = [&](size_t bytes) {
    char* p = ws + off;
    off += (bytes + 255) & ~(size_t)255;
    return p;
  };
  ushort_t* w1b = (ushort_t*)alloc(sizeof(ushort_t) * NH * NI);
  ushort_t* wihb = (ushort_t*)alloc(sizeof(ushort_t) * NG * NH);
  ushort_t* whhb = (ushort_t*)alloc(sizeof(ushort_t) * NG * NH);
  ushort_t* w3b = (ushort_t*)alloc(sizeof(ushort_t) * NA * NH);
  ushort_t* fb = (ushort_t*)alloc(sizeof(ushort_t) * (size_t)NB * NTT * NH);  // f, then hs (in-place)
  float* cbuf = (float*)alloc(sizeof(float) * NB * NH);
  uint_t* flags = (uint_t*)alloc(sizeof(uint_t) * 64 * 32);
  if (off > ws_size) {
    hipMemsetAsync(d_out, 0xFF, 256, stream);  // NaN sentinel: ws too small
    return;
  }

  // scratch carved out of d_out (dead before fc3 writes d_out):
  ushort_t* xb = (ushort_t*)d_out;                           // bf16 x for fc1
  ushort_t* hseq = (ushort_t*)d_out;                         // [CHUNK+1][NB][NH] (reuses xb)
  ushort_t* gxc = (ushort_t*)d_out + (size_t)NB * NTT * NI;  // [CHUNK][64][NB][64]

  auto cast = [&](const float* src, ushort_t* dst, int n) {
    cast_f32_bf16<<<dim3((n / 4 + 255) / 256), dim3(256), 0, stream>>>(src, dst, n);
  };
  cast(x, xb, NB * NTT * NI);
  cast(w1, w1b, NH * NI);
  cast(w_ih, wihb, NG * NH);
  cast(w_hh, whhb, NG * NH);
  cast(w3, w3b, NA * NH);

  // fc1 + tanh -> f (bf16)
  gemm_nt<1><<<dim3(NH / 128, NB * NTT / 128), dim3(256), 0, stream>>>(
      (const short*)xb, (const short*)w1b, b1, nullptr, fb, NB * NTT, NH, NI, 0);

  hipMemsetAsync(flags, 0, sizeof(uint_t) * 64 * 32, stream);
  int ldsz = 64 * NH * 2 + 64 * 65 * 4;
  hipFuncSetAttribute(reinterpret_cast<const void*>(&lstm_scan),
                      hipFuncAttributeMaxDynamicSharedMemorySize, ldsz);

  for (int chunk = 0; chunk < NTT / CHUNK; ++chunk) {
    int t0 = chunk * CHUNK;
    gemm_nt<2><<<dim3(NG / 128, NB * CHUNK / 128), dim3(256), 0, stream>>>(
        (const short*)fb, (const short*)wihb, b_ih, b_hh, gxc, NB * CHUNK, NG, NH, t0);
    lstm_scan<<<dim3(64), dim3(512), ldsz, stream>>>(
        whhb, gxc, hseq, cbuf, fb, flags, t0, (uint_t)(chunk * (CHUNK + 1)));
  }

  // fc3 head -> d_out (fp32)
  gemm_nt<0><<<dim3(NA / 128, NB * NTT / 128), dim3(256), 0, stream>>>(
      (const short*)fb, (const short*)w3b, b3, nullptr, d_out, NB * NTT, NA, NH, 0);
}

// Round 5
// 5463.257 us; speedup vs baseline: 1.5122x; 1.1645x over previous
//
#include <hip/hip_runtime.h>
#include <cstdint>
#include <cstddef>

#define DEVI __device__ __forceinline__

typedef __attribute__((ext_vector_type(8))) short bf16x8;
typedef __attribute__((ext_vector_type(4))) float f32x4;
typedef unsigned short ushort_t;
typedef unsigned int uint_t;

// problem dims (fixed)
constexpr int NB = 64;    // batch
constexpr int NTT = 512;  // seq len
constexpr int NI = 512;   // input feat
constexpr int NH = 1024;  // hidden
constexpr int NA = 512;   // out feat
constexpr int NG = 4096;  // 4*NH
constexpr int CHUNK = 64; // scan chunk (timesteps per launch)

DEVI float bf2f(ushort_t u) { union { uint_t i; float f; } v; v.i = ((uint_t)u) << 16; return v.f; }
DEVI ushort_t f2bf(float f) {
  union { float f; uint_t i; } v; v.f = f;
  uint_t x = v.i;
  return (ushort_t)((x + 0x7fffu + ((x >> 16) & 1u)) >> 16);
}

DEVI void gload_lds16(const void* g, void* l) {
  __builtin_amdgcn_global_load_lds((__attribute__((address_space(1))) void*)g,
                                   (__attribute__((address_space(3))) void*)l, 16, 0, 0);
}

// ---------------- cast fp32 -> bf16 ----------------
__global__ __launch_bounds__(256) void cast_f32_bf16(const float* __restrict__ in,
                                                     ushort_t* __restrict__ out, int n) {
  int i = (blockIdx.x * 256 + threadIdx.x) * 4;
  if (i >= n) return;
  float4 v = *(const float4*)(in + i);
  ushort4 o;
  o.x = f2bf(v.x); o.y = f2bf(v.y); o.z = f2bf(v.z); o.w = f2bf(v.w);
  *(ushort4*)(out + i) = o;
}

// ---------------- generic NT GEMM: C[M,N] = A[M,K] * B[N,K]^T ----------------
// MODE 0: fp32 out, +bias0                              (fc3 -> d_out)
// MODE 1: bf16 out, tanh(acc+bias0)                     (fc1 -> f)
// MODE 2: chunked gx: A rows are (b, t0+tl) of f [B,T,H]; bf16 out,
//         acc+bias0+bias1, scatter to gxc[tl][wg][b][g*16+u]
template <int MODE>
__global__ __launch_bounds__(256) void gemm_nt(const short* __restrict__ A,
                                               const short* __restrict__ Bm,
                                               const float* __restrict__ bias0,
                                               const float* __restrict__ bias1,
                                               void* __restrict__ Cout,
                                               int M, int N, int K, int t0) {
  __shared__ short As[128 * 32];
  __shared__ short Bs[128 * 32];
  const int tid = threadIdx.x;
  const int wave = tid >> 6, lane = tid & 63;
  const int m0 = blockIdx.y * 128, n0 = blockIdx.x * 128;
  const int wr = wave >> 1, wc = wave & 1;

  f32x4 zero = {0.f, 0.f, 0.f, 0.f};
  f32x4 acc[4][4];
#pragma unroll
  for (int i = 0; i < 4; ++i)
#pragma unroll
    for (int j = 0; j < 4; ++j) acc[i][j] = zero;

  const int lrow = lane >> 2;       // 0..15
  const int lk = (lane & 3) * 8;    // element offset within 32

  for (int kt = 0; kt < K; kt += 32) {
#pragma unroll
    for (int c = 0; c < 2; ++c) {
      int q = wave + 4 * c;              // chunk 0..7, uniform per wave
      int row = m0 + q * 16 + lrow;
      long arow = (MODE == 2) ? ((long)(row >> 6) * NTT + t0 + (row & 63)) : (long)row;
      gload_lds16(A + arow * K + kt + lk, As + q * 512);
      gload_lds16(Bm + (long)(n0 + q * 16 + lrow) * K + kt + lk, Bs + q * 512);
    }
    __syncthreads();  // drains vmcnt for global_load_lds

    bf16x8 av[4], bv[4];
#pragma unroll
    for (int i = 0; i < 4; ++i) {
      int row = wr * 64 + i * 16 + (lane & 15);
      av[i] = *(const bf16x8*)(As + row * 32 + (lane >> 4) * 8);
    }
#pragma unroll
    for (int j = 0; j < 4; ++j) {
      int col = wc * 64 + j * 16 + (lane & 15);
      bv[j] = *(const bf16x8*)(Bs + col * 32 + (lane >> 4) * 8);
    }
#pragma unroll
    for (int i = 0; i < 4; ++i)
#pragma unroll
      for (int j = 0; j < 4; ++j)
        acc[i][j] = __builtin_amdgcn_mfma_f32_16x16x32_bf16(av[i], bv[j], acc[i][j], 0, 0, 0);
    __syncthreads();
  }

  const int fq = lane >> 4, fr = lane & 15;
#pragma unroll
  for (int i = 0; i < 4; ++i) {
#pragma unroll
    for (int j = 0; j < 4; ++j) {
      int gcol = n0 + wc * 64 + j * 16 + fr;
      float bsum = bias0[gcol];
      if (MODE == 2) bsum += bias1[gcol];
#pragma unroll
      for (int r = 0; r < 4; ++r) {
        int gm = m0 + wr * 64 + i * 16 + fq * 4 + r;
        float v = acc[i][j][r] + bsum;
        if (MODE == 0) {
          ((float*)Cout)[(long)gm * N + gcol] = v;
        } else if (MODE == 1) {
          ((ushort_t*)Cout)[(long)gm * N + gcol] = f2bf(tanhf(v));
        } else {
          int b = gm >> 6, tl = gm & 63;  // chunk row = b*64 + tl
          int wgp = (gcol >> 4) & 63, g = gcol >> 10, u = gcol & 15;
          ((ushort_t*)Cout)[((((long)tl * 64 + wgp) * 64 + b) << 6) + g * 16 + u] = f2bf(v);
        }
      }
    }
  }
}

// ---------------- persistent LSTM scan (one chunk of CHUNK timesteps) ----------------
// 64 WGs x 512 threads. WG owns 64 gate rows = 16 hidden units (wg*16+u).
// Local row n = gate*16 + u; global gate row = gate*1024 + wg*16 + u.
// LDS: wlds[64][1024] bf16 XOR-swizzled (byte ^= (n&7)<<4); pre[64][65] fp32.
// h passes through rotating hseq slots (relaxed agent stores -> LLC; plain loads).
// Grid sync: per-WG flag cachelines; wave0 polls all 64. Release = s_waitcnt
// vmcnt(0) only (payload stores are agent-atomics; avoids buffer_wbl2).
// KEY (R5): h A-fragments are bulk-staged into registers (areg[32]) so all 32
// 16B loads are in flight at once -> one LLC latency, not 16 serialized trips.
__global__ __launch_bounds__(512, 2) void lstm_scan(const ushort_t* __restrict__ whh,
                                                    const ushort_t* __restrict__ gxc,  // [CHUNK][64][NB][64]
                                                    ushort_t* __restrict__ hseq,       // [CHUNK+1][NB][NH]
                                                    float* __restrict__ cbuf,          // [NB][NH]
                                                    ushort_t* __restrict__ hs,         // [NB][NTT][NH]
                                                    uint_t* __restrict__ flags,
                                                    int t0, uint_t tbase) {
  extern __shared__ char smem[];
  float* pre = (float*)(smem + 64 * NH * 2);  // [64][65] fp32
  const int wg = blockIdx.x, tid = threadIdx.x;
  const int wave = tid >> 6, lane = tid & 63;
  const int fq = lane >> 4, fr = lane & 15;

  // stage weights into swizzled LDS
  for (int idx = tid; idx < 64 * 128; idx += 512) {
    int n = idx >> 7, kc = idx & 127;  // kc: 16B chunk (8 bf16)
    int grow = (n >> 4) * NH + wg * 16 + (n & 15);
    bf16x8 w = *(const bf16x8*)(whh + (long)grow * NH + kc * 8);
    int byteoff = n * 2048 + ((kc * 16) ^ ((n & 7) << 4));
    *(bf16x8*)(smem + byteoff) = w;
  }
  const int cb = tid >> 3, cup = tid & 7;  // thread owns (b=cb, u=2*cup, 2*cup+1)
  float c0, c1;
  if (t0 == 0) {
    uint_t* p = (uint_t*)(hseq + cb * NH + wg * 16 + cup * 2);
    __hip_atomic_store(p, 0u, __ATOMIC_RELAXED, __HIP_MEMORY_SCOPE_AGENT);
    c0 = 0.f; c1 = 0.f;
  } else {
    c0 = cbuf[cb * NH + wg * 16 + cup * 2];
    c1 = cbuf[cb * NH + wg * 16 + cup * 2 + 1];
  }

  const int bb = (wave & 3) * 16;        // batch base for this wave
  const int nb0 = (wave >> 2) * 32;      // n base (two 16-tiles)
  const int abrow = bb + fr;             // A-frag row (batch)
  f32x4 zero = {0.f, 0.f, 0.f, 0.f};

  ushort_t gxr[8];
  auto prefetch = [&](int tl) {
#pragma unroll
    for (int jt = 0; jt < 2; ++jt) {
      int n = nb0 + jt * 16 + fr;
#pragma unroll
      for (int r = 0; r < 4; ++r) {
        int b = bb + fq * 4 + r;
        gxr[jt * 4 + r] = gxc[((((long)tl * 64 + wg) * 64 + b) << 6) + n];
      }
    }
  };
  auto poll = [&](uint_t t) {
    if (tid < 64) {
      uint_t* fp = flags + tid * 32;
      for (;;) {
        uint_t v = __hip_atomic_load(fp, __ATOMIC_RELAXED, __HIP_MEMORY_SCOPE_AGENT);
        if (__all(v >= t)) break;
        __builtin_amdgcn_s_sleep(1);
      }
    }
  };

  // initial barrier: weights staged, h slot0 + c ready
  asm volatile("s_waitcnt vmcnt(0)" ::: "memory");
  __syncthreads();
  if (tid == 0)
    __hip_atomic_store(flags + wg * 32, tbase + 1, __ATOMIC_RELAXED, __HIP_MEMORY_SCOPE_AGENT);
  prefetch(0);
  poll(tbase + 1);
  __syncthreads();

  for (int tl = 0; tl < CHUNK; ++tl) {
    const ushort_t* hc = hseq + (size_t)tl * (NB * NH);
    // bulk-stage this step's A-fragments: 32 x 16B loads, all in flight
    bf16x8 areg[32];
#pragma unroll
    for (int ks = 0; ks < 32; ++ks)
      areg[ks] = *(const bf16x8*)(hc + abrow * NH + ks * 32 + fq * 8);

    f32x4 acc0 = zero, acc1 = zero;
#pragma unroll
    for (int ks = 0; ks < 32; ++ks) {
      int n0 = nb0 + fr, n1 = nb0 + 16 + fr;
      int b0off = n0 * 2048 + ((ks * 64 + fq * 16) ^ ((n0 & 7) << 4));
      int b1off = n1 * 2048 + ((ks * 64 + fq * 16) ^ ((n1 & 7) << 4));
      bf16x8 w0 = *(const bf16x8*)(smem + b0off);
      bf16x8 w1 = *(const bf16x8*)(smem + b1off);
      acc0 = __builtin_amdgcn_mfma_f32_16x16x32_bf16(areg[ks], w0, acc0, 0, 0, 0);
      acc1 = __builtin_amdgcn_mfma_f32_16x16x32_bf16(areg[ks], w1, acc1, 0, 0, 0);
    }
    // preactivations (+gx) -> LDS
#pragma unroll
    for (int r = 0; r < 4; ++r) {
      int b = bb + fq * 4 + r;
      pre[b * 65 + nb0 + fr] = acc0[r] + bf2f(gxr[r]);
      pre[b * 65 + nb0 + 16 + fr] = acc1[r] + bf2f(gxr[4 + r]);
    }
    __syncthreads();
    // gates + state update for (cb, u0, u1)
    float h01[2];
#pragma unroll
    for (int k = 0; k < 2; ++k) {
      int u = cup * 2 + k;
      float xi = pre[cb * 65 + 0 * 16 + u];
      float xf = pre[cb * 65 + 1 * 16 + u];
      float xg = pre[cb * 65 + 2 * 16 + u];
      float xo = pre[cb * 65 + 3 * 16 + u];
      float ig = 1.f / (1.f + __expf(-xi));
      float fg = 1.f / (1.f + __expf(-xf));
      float gg = tanhf(xg);
      float og = 1.f / (1.f + __expf(-xo));
      float& c = k ? c1 : c0;
      c = fg * c + ig * gg;
      h01[k] = og * tanhf(c);
    }
    uint_t hpack = (uint_t)f2bf(h01[0]) | ((uint_t)f2bf(h01[1]) << 16);
    uint_t* hdst = (uint_t*)(hseq + (size_t)(tl + 1) * (NB * NH) + cb * NH + wg * 16 + cup * 2);
    __hip_atomic_store(hdst, hpack, __ATOMIC_RELAXED, __HIP_MEMORY_SCOPE_AGENT);
    if (tl == CHUNK - 1) {  // hand h(final) to next chunk's slot 0
      uint_t* h0 = (uint_t*)(hseq + cb * NH + wg * 16 + cup * 2);
      __hip_atomic_store(h0, hpack, __ATOMIC_RELAXED, __HIP_MEMORY_SCOPE_AGENT);
    }

    // ---- grid barrier: vmcnt-drain release, no wbl2 ----
    asm volatile("s_waitcnt vmcnt(0)" ::: "memory");  // h atomic stores acked at LLC
    __syncthreads();                                  // all threads of WG drained
    uint_t t = tbase + 2 + tl;
    if (tid == 0)
      __hip_atomic_store(flags + wg * 32, t, __ATOMIC_RELAXED, __HIP_MEMORY_SCOPE_AGENT);
    // off-critical-path work overlapped with the wait:
    *(uint_t*)(hs + ((size_t)cb * NTT + t0 + tl) * NH + wg * 16 + cup * 2) = hpack;
    if (tl + 1 < CHUNK) prefetch(tl + 1);
    poll(t);
    __syncthreads();
    asm volatile("" ::: "memory");
  }
  // persist c for next chunk
  cbuf[cb * NH + wg * 16 + cup * 2] = c0;
  cbuf[cb * NH + wg * 16 + cup * 2 + 1] = c1;
}

// ---------------- host ----------------
extern "C" void kernel_launch(void* const* d_in, const int* in_sizes, int n_in,
                              void* d_out, int out_size, void* d_ws, size_t ws_size,
                              hipStream_t stream) {
  const float* x = (const float*)d_in[0];
  const float* w1 = (const float*)d_in[1];
  const float* b1 = (const float*)d_in[2];
  const float* w_ih = (const float*)d_in[3];
  const float* w_hh = (const float*)d_in[4];
  const float* b_ih = (const float*)d_in[5];
  const float* b_hh = (const float*)d_in[6];
  const float* w3 = (const float*)d_in[7];
  const float* b3 = (const float*)d_in[8];

  char* ws = (char*)d_ws;
  size_t off = 0;
  auto alloc = [&](size_t bytes) {
    char* p = ws + off;
    off += (bytes + 255) & ~(size_t)255;
    return p;
  };
  ushort_t* w1b = (ushort_t*)alloc(sizeof(ushort_t) * NH * NI);
  ushort_t* wihb = (ushort_t*)alloc(sizeof(ushort_t) * NG * NH);
  ushort_t* whhb = (ushort_t*)alloc(sizeof(ushort_t) * NG * NH);
  ushort_t* w3b = (ushort_t*)alloc(sizeof(ushort_t) * NA * NH);
  ushort_t* fb = (ushort_t*)alloc(sizeof(ushort_t) * (size_t)NB * NTT * NH);  // f, then hs (in-place)
  float* cbuf = (float*)alloc(sizeof(float) * NB * NH);
  uint_t* flags = (uint_t*)alloc(sizeof(uint_t) * 64 * 32);
  if (off > ws_size) {
    hipMemsetAsync(d_out, 0xFF, 256, stream);  // NaN sentinel: ws too small
    return;
  }

  // scratch carved out of d_out (dead before fc3 writes d_out):
  ushort_t* xb = (ushort_t*)d_out;                           // bf16 x for fc1
  ushort_t* hseq = (ushort_t*)d_out;                         // [CHUNK+1][NB][NH] (reuses xb)
  ushort_t* gxc = (ushort_t*)d_out + (size_t)NB * NTT * NI;  // [CHUNK][64][NB][64]

  auto cast = [&](const float* src, ushort_t* dst, int n) {
    cast_f32_bf16<<<dim3((n / 4 + 255) / 256), dim3(256), 0, stream>>>(src, dst, n);
  };
  cast(x, xb, NB * NTT * NI);
  cast(w1, w1b, NH * NI);
  cast(w_ih, wihb, NG * NH);
  cast(w_hh, whhb, NG * NH);
  cast(w3, w3b, NA * NH);

  // fc1 + tanh -> f (bf16)
  gemm_nt<1><<<dim3(NH / 128, NB * NTT / 128), dim3(256), 0, stream>>>(
      (const short*)xb, (const short*)w1b, b1, nullptr, fb, NB * NTT, NH, NI, 0);

  hipMemsetAsync(flags, 0, sizeof(uint_t) * 64 * 32, stream);
  int ldsz = 64 * NH * 2 + 64 * 65 * 4;
  hipFuncSetAttribute(reinterpret_cast<const void*>(&lstm_scan),
                      hipFuncAttributeMaxDynamicSharedMemorySize, ldsz);

  for (int chunk = 0; chunk < NTT / CHUNK; ++chunk) {
    int t0 = chunk * CHUNK;
    gemm_nt<2><<<dim3(NG / 128, NB * CHUNK / 128), dim3(256), 0, stream>>>(
        (const short*)fb, (const short*)wihb, b_ih, b_hh, gxc, NB * CHUNK, NG, NH, t0);
    lstm_scan<<<dim3(64), dim3(512), ldsz, stream>>>(
        whhb, gxc, hseq, cbuf, fb, flags, t0, (uint_t)(chunk * (CHUNK + 1)));
  }

  // fc3 head -> d_out (fp32)
  gemm_nt<0><<<dim3(NA / 128, NB * NTT / 128), dim3(256), 0, stream>>>(
      (const short*)fb, (const short*)w3b, b3, nullptr, d_out, NB * NTT, NA, NH, 0);
}